// Round 5
// baseline (356.924 us; speedup 1.0000x reference)
//
#include <hip/hip_runtime.h>

// Problem constants: B=32, T=1024, IN=1024, OUT=1024
// M = B*T = 32768, K = IN = 1024, N = OUT = 1024
#define M_DIM 32768
#define N_DIM 1024
#define K_DIM 1024
#define T_DIM 1024
#define B_DIM 32
#define NCHUNK 16
#define CHUNK_T 64    // T_DIM / NCHUNK; one chunk per GEMM wave-half (wm)

typedef unsigned int uint32;
typedef __attribute__((ext_vector_type(8))) short short8;       // 8 bf16 (MFMA A/B frag)
typedef __attribute__((ext_vector_type(8))) unsigned short ushort8v;
typedef __attribute__((ext_vector_type(4))) float floatx4;      // MFMA C/D frag

__device__ __forceinline__ unsigned short f2bf(float f) {
    uint32 u = __float_as_uint(f);
    uint32 r = u + 0x7fffu + ((u >> 16) & 1u);
    return (unsigned short)(r >> 16);
}

__device__ __forceinline__ void async_load16(const void* g, void* s) {
    __builtin_amdgcn_global_load_lds(
        (const __attribute__((address_space(1))) void*)g,
        (__attribute__((address_space(3))) void*)s,
        16, 0, 0);
}

__device__ __forceinline__ uint32 cvt_pk_bf16(float lo, float hi) {
    uint32 d;
    asm volatile("v_cvt_pk_bf16_f32 %0, %1, %2" : "=v"(d) : "v"(lo), "v"(hi));
    return d;
}

// ---------------------------------------------------------------------------
// fp32 -> bf16 cast: now only used for W (4 MB read, ~3 us).
// ---------------------------------------------------------------------------
__global__ void cast_f32_bf16_x8(const float* __restrict__ src,
                                 unsigned short* __restrict__ dst, int n8) {
    int i = blockIdx.x * blockDim.x + threadIdx.x;
    if (i < n8) {
        const float4* s4 = (const float4*)src;
        float4 v0 = s4[(size_t)i * 2];
        float4 v1 = s4[(size_t)i * 2 + 1];
        ushort8v o;
        o[0] = f2bf(v0.x); o[1] = f2bf(v0.y); o[2] = f2bf(v0.z); o[3] = f2bf(v0.w);
        o[4] = f2bf(v1.x); o[5] = f2bf(v1.y); o[6] = f2bf(v1.z); o[7] = f2bf(v1.w);
        ((ushort8v*)dst)[i] = o;
    }
}

// ---------------------------------------------------------------------------
// Fused-cast MFMA GEMM: reads A as fp32 DIRECTLY (A-cast kernel deleted).
// Tile BM=128 x BN=512, BK=32, 512 threads (8 waves, 2M x 4N), 2 blocks/CU
// (LDS 80 KB). A (8 KB/ktile fp32->bf16) is reg-staged: fp32 global loads
// issued at loop top, cvt_pk + swizzled ds_write AFTER compute (T14 split).
// B (32 KB/ktile) keeps async global_load_lds with pre-swizzled source.
// Double-buffered, one __syncthreads per k-step (R4-verified schedule).
// XOR swizzle: 16B chunk c at row r -> c ^ ((r>>1)&3)  (rows are 64 B).
// Epilogue: bias + bf16 C write + fused chunk-carry (one chunk per wave wm).
// ---------------------------------------------------------------------------
#define NKS (K_DIM / 32)    // 32 k-steps

#define STAGE_B(BsD, k0)                                                  \
  {                                                                       \
    _Pragma("unroll")                                                     \
    for (int q = 0; q < 4; ++q) {                                         \
      int slot = q * 512 + tid;                                           \
      int row  = slot >> 2;                                               \
      int ch   = slot & 3;                                                \
      int sc   = ch ^ ((row >> 1) & 3);                                   \
      async_load16(Bg + (size_t)(bn0 + row) * K_DIM + (k0) + sc * 8,      \
                   &BsD[slot * 8]);                                       \
    }                                                                     \
  }

#define LOAD_A(k0)                                                        \
  {                                                                       \
    const float* p = Ag + (size_t)(bm0 + arow) * K_DIM + (k0) + ach * 8;  \
    ar0 = ((const float4*)p)[0];                                          \
    ar1 = ((const float4*)p)[1];                                          \
  }

#define WRITE_A(AsD)                                                      \
  {                                                                       \
    uint4 wv;                                                             \
    wv.x = cvt_pk_bf16(ar0.x, ar0.y);                                     \
    wv.y = cvt_pk_bf16(ar0.z, ar0.w);                                     \
    wv.z = cvt_pk_bf16(ar1.x, ar1.y);                                     \
    wv.w = cvt_pk_bf16(ar1.z, ar1.w);                                     \
    *(uint4*)&AsD[arow * 32 + ((ach ^ ((arow >> 1) & 3)) * 8)] = wv;      \
  }

#define COMPUTE_STEP(AsS, BsS)                                            \
  {                                                                       \
    short8 af[4], bfr[8];                                                 \
    _Pragma("unroll")                                                     \
    for (int m = 0; m < 4; ++m) {                                         \
      int rr = wm * 64 + m * 16 + l15;                                    \
      af[m] = *(const short8*)&AsS[rr * 32 + ((quad ^ ((rr >> 1) & 3)) * 8)]; \
    }                                                                     \
    _Pragma("unroll")                                                     \
    for (int n = 0; n < 8; ++n) {                                         \
      int rb = wn * 128 + n * 16 + l15;                                   \
      bfr[n] = *(const short8*)&BsS[rb * 32 + ((quad ^ ((rb >> 1) & 3)) * 8)]; \
    }                                                                     \
    _Pragma("unroll")                                                     \
    for (int m = 0; m < 4; ++m)                                           \
      _Pragma("unroll")                                                   \
      for (int n = 0; n < 8; ++n)                                         \
        acc[m][n] = __builtin_amdgcn_mfma_f32_16x16x32_bf16(              \
            af[m], bfr[n], acc[m][n], 0, 0, 0);                           \
  }

__global__ __launch_bounds__(512) void gemm_fusedcast(
    const float* __restrict__ Ag,           // [M, K] fp32 (= X)
    const unsigned short* __restrict__ Bg,  // [N, K] bf16
    const float* __restrict__ bias,         // [N]
    const float* __restrict__ decay,        // [N]
    unsigned short* outBf,                  // [M, N] bf16 (or null)
    float* outF,                            // [M, N] fp32 (or null)
    float* carry) {                         // [B, NCHUNK, N] (or null)
    __shared__ unsigned short As0[128 * 32];
    __shared__ unsigned short As1[128 * 32];
    __shared__ unsigned short Bs0[512 * 32];
    __shared__ unsigned short Bs1[512 * 32];

    const int tid  = threadIdx.x;            // 0..511
    const int lane = tid & 63;
    const int wid  = tid >> 6;               // 0..7
    const int l15  = lane & 15;
    const int quad = lane >> 4;
    const int wm   = wid >> 2;               // 0..1  (M half)
    const int wn   = wid & 3;                // 0..3  (N quarter)

    // XCD-aware remap: 512 blocks; xcd owns M-panels [xcd*32, xcd*32+32),
    // the two N-halves of a panel are consecutive (twin shares A in L2).
    const int L   = blockIdx.x;
    const int xcd = L & 7;
    const int s   = L >> 3;                  // 0..63
    const int bn0 = (s & 1) * 512;
    const int bm0 = (xcd * 32 + (s >> 1)) * 128;

    // A staging map: thread -> (row = tid>>2, 8-col chunk = tid&3)
    const int arow = tid >> 2;
    const int ach  = tid & 3;
    float4 ar0, ar1;

    floatx4 acc[4][8];
#pragma unroll
    for (int m = 0; m < 4; ++m)
#pragma unroll
        for (int n = 0; n < 8; ++n)
            acc[m][n] = (floatx4){0.f, 0.f, 0.f, 0.f};

    // Prologue: tile 0 into buffer 0.
    LOAD_A(0);
    STAGE_B(Bs0, 0);
    WRITE_A(As0);
    __syncthreads();

#pragma unroll 1
    for (int kt = 0; kt < NKS; kt += 2) {
        // ---- step kt (buffers 0), staging kt+1 into buffers 1 ----
        LOAD_A((kt + 1) * 32);               // kt+1 <= 31 always
        STAGE_B(Bs1, (kt + 1) * 32);
        COMPUTE_STEP(As0, Bs0);
        WRITE_A(As1);
        __syncthreads();
        // ---- step kt+1 (buffers 1), staging kt+2 into buffers 0 ----
        if (kt + 2 < NKS) {
            LOAD_A((kt + 2) * 32);
            STAGE_B(Bs0, (kt + 2) * 32);
        }
        COMPUTE_STEP(As1, Bs1);
        if (kt + 2 < NKS) WRITE_A(As0);
        __syncthreads();
    }

    // C/D layout: col = lane&15, row = quad*4 + reg
#pragma unroll
    for (int n = 0; n < 8; ++n) {
        int col = bn0 + wn * 128 + n * 16 + l15;
        float bb = bias[col];
#pragma unroll
        for (int m = 0; m < 4; ++m) {
            int rowb = bm0 + wm * 64 + m * 16 + quad * 4;
#pragma unroll
            for (int r = 0; r < 4; ++r) {
                float v = acc[m][n][r] + bb;
                size_t idx = (size_t)(rowb + r) * N_DIM + col;
                if (outBf) outBf[idx] = f2bf(v);
                else       outF[idx]  = v;
            }
        }
    }

    // ---- fused chunk-carry epilogue (R1/R4-verified math; wave wm owns
    // exactly one 64-row chunk here) ----
    // U = (1-a)*sum_{rloc} a^(63-rloc)*acc + bias*(1-a^64), rloc = m*16+quad*4+r
    if (carry) {
        const int bIdx = bm0 >> 10;                       // / T_DIM
        const int g    = ((bm0 & (T_DIM - 1)) >> 6) + wm; // chunk index
#pragma unroll
        for (int n = 0; n < 8; ++n) {
            int col = bn0 + wn * 128 + n * 16 + l15;
            float a   = decay[col];
            float bb  = bias[col];
            float a2  = a * a;
            float a4  = a2 * a2;
            float a8  = a4 * a4;
            float a12 = a8 * a4;
            float a64 = a12 * a4;          // a^16
            a64 = a64 * a64;               // a^32
            a64 = a64 * a64;               // a^64
            float w = (quad == 0) ? a12 : (quad == 1) ? a8
                    : (quad == 2) ? a4  : 1.0f;
            float sacc = 0.f;
#pragma unroll
            for (int m = 3; m >= 0; --m) {
#pragma unroll
                for (int r = 3; r >= 0; --r) {
                    sacc += w * acc[m][n][r];
                    w *= a;
                }
                if (m) w *= a12;           // row gap 13 across fragments
            }
            sacc += __shfl_xor(sacc, 16);
            sacc += __shfl_xor(sacc, 32);
            float U = (1.0f - a) * sacc + bb * (1.0f - a64);
            if (quad == 0)
                carry[((size_t)bIdx * NCHUNK + g) * N_DIM + col] = U;
        }
    }
}

// ---------------------------------------------------------------------------
// Apply pass, 4-wide over o: uint2 loads (8B/lane), float4 stores (16B/lane).
// Thread <-> (b, chunk, o4): o4 = tid&255, chunk = (tid>>8)&15, b = tid>>12.
// 131072 threads = 2048 waves = 8 waves/CU; 32-deep load pipeline.
// ---------------------------------------------------------------------------
__global__ __launch_bounds__(256) void scan_apply4(
    const uint2* __restrict__ cur4,           // [M, N/4] (2x bf16-pair)
    const float* __restrict__ decay,
    const float* __restrict__ carry,          // [B, NCHUNK, N]
    float* __restrict__ out) {                // [M, N] fp32
    int tid   = blockIdx.x * 256 + threadIdx.x;   // 0 .. 131071
    int o4    = tid & 255;
    int chunk = (tid >> 8) & (NCHUNK - 1);
    int b     = tid >> 12;
    int o     = o4 * 4;
    size_t base = ((size_t)b * T_DIM + (size_t)chunk * CHUNK_T) * (N_DIM / 4) + o4;
    float4 av = *(const float4*)&decay[o];
    float a0 = av.x, a1 = av.y, a2 = av.z, a3 = av.w;
    float c0 = 1.f - a0, c1 = 1.f - a1, c2 = 1.f - a2, c3 = 1.f - a3;

    float A0 = a0, A1 = a1, A2 = a2, A3 = a3;
#pragma unroll
    for (int i = 0; i < 6; ++i) { A0 *= A0; A1 *= A1; A2 *= A2; A3 *= A3; }  // a^64

    float u0 = 0.f, u1 = 0.f, u2 = 0.f, u3 = 0.f;
    const float* cb = carry + (size_t)b * NCHUNK * N_DIM + o;
    for (int i = 0; i < chunk; ++i) {         // wave-uniform trip count
        float4 cv = *(const float4*)&cb[(size_t)i * N_DIM];
        u0 = cv.x + A0 * u0;
        u1 = cv.y + A1 * u1;
        u2 = cv.z + A2 * u2;
        u3 = cv.w + A3 * u3;
    }

    float4* out4 = (float4*)out;
    for (int t0 = 0; t0 < CHUNK_T; t0 += 32) {
        uint2 x[32];
#pragma unroll
        for (int k = 0; k < 32; ++k)
            x[k] = cur4[base + (size_t)(t0 + k) * (N_DIM / 4)];
#pragma unroll
        for (int k = 0; k < 32; ++k) {
            float v0 = __uint_as_float(x[k].x << 16);
            float v1 = __uint_as_float(x[k].x & 0xffff0000u);
            float v2 = __uint_as_float(x[k].y << 16);
            float v3 = __uint_as_float(x[k].y & 0xffff0000u);
            u0 = a0 * u0 + c0 * v0;
            u1 = a1 * u1 + c1 * v1;
            u2 = a2 * u2 + c2 * v2;
            u3 = a3 * u3 + c3 * v3;
            out4[base + (size_t)(t0 + k) * (N_DIM / 4)] = (float4){u0, u1, u2, u3};
        }
    }
}

// ---------------------------------------------------------------------------
// Fallbacks (only used if workspace too small for the bf16 path)
// ---------------------------------------------------------------------------
__global__ void scan_f32_inplace(float* __restrict__ buf,
                                 const float* __restrict__ decay) {
    int tid = blockIdx.x * 64 + threadIdx.x;
    int o = tid & (N_DIM - 1);
    size_t base = ((size_t)(tid >> 10) << 20) + o;
    float a = decay[o];
    float c = 1.f - a;
    float u = 0.f;
    for (int t0 = 0; t0 < 1024; t0 += 16) {
        float x[16];
#pragma unroll
        for (int k = 0; k < 16; ++k)
            x[k] = buf[base + (size_t)(t0 + k) * N_DIM];
#pragma unroll
        for (int k = 0; k < 16; ++k) {
            u = a * u + c * x[k];
            buf[base + (size_t)(t0 + k) * N_DIM] = u;
        }
    }
}

__global__ void gemm_naive(const float* __restrict__ X, const float* __restrict__ W,
                           const float* __restrict__ bias, float* __restrict__ out) {
    __shared__ float As[16][17], Bs[16][17];
    int tx = threadIdx.x, ty = threadIdx.y;
    int m0 = blockIdx.y * 16, n0 = blockIdx.x * 16;
    float acc = 0.f;
    for (int k0 = 0; k0 < K_DIM; k0 += 16) {
        As[ty][tx] = X[(size_t)(m0 + ty) * K_DIM + k0 + tx];
        Bs[ty][tx] = W[(size_t)(n0 + ty) * K_DIM + k0 + tx];
        __syncthreads();
#pragma unroll
        for (int kk = 0; kk < 16; ++kk) acc += As[ty][kk] * Bs[tx][kk];
        __syncthreads();
    }
    out[(size_t)(m0 + ty) * N_DIM + n0 + tx] = acc + bias[n0 + tx];
}

// ---------------------------------------------------------------------------
extern "C" void kernel_launch(void* const* d_in, const int* in_sizes, int n_in,
                              void* d_out, int out_size, void* d_ws, size_t ws_size,
                              hipStream_t stream) {
    const float* X     = (const float*)d_in[0];  // [B,T,IN]  = [M,K]
    const float* Wt    = (const float*)d_in[1];  // [OUT,IN]  = [N,K]
    const float* bias  = (const float*)d_in[2];  // [OUT]
    const float* decay = (const float*)d_in[3];  // [OUT]
    float* out = (float*)d_out;                  // [B,T,OUT] = [M,N]

    const size_t W_bytes  = (size_t)N_DIM * K_DIM * 2;            // 2 MB
    const size_t C_bytes  = (size_t)M_DIM * N_DIM * 2;            // 64 MB
    const size_t cr_bytes = (size_t)B_DIM * NCHUNK * N_DIM * 4;   // 2 MB
    const size_t need_mid  = W_bytes;
    const size_t need_full = W_bytes + C_bytes + cr_bytes;

    const int nW8 = N_DIM * K_DIM / 8;

    if (ws_size >= need_full) {
        unsigned short* Wbf = (unsigned short*)d_ws;
        unsigned short* Cbf = (unsigned short*)((char*)d_ws + W_bytes);
        float* carry = (float*)((char*)d_ws + W_bytes + C_bytes);
        cast_f32_bf16_x8<<<(nW8 + 255) / 256, 256, 0, stream>>>(Wt, Wbf, nW8);
        gemm_fusedcast<<<dim3(M_DIM / 128 * (N_DIM / 512)), 512, 0, stream>>>(
            X, Wbf, bias, decay, Cbf, nullptr, carry);
        const int apply_threads = B_DIM * NCHUNK * N_DIM / 4;     // 131072
        scan_apply4<<<apply_threads / 256, 256, 0, stream>>>(
            (const uint2*)Cbf, decay, carry, out);
    } else if (ws_size >= need_mid) {
        unsigned short* Wbf = (unsigned short*)d_ws;
        cast_f32_bf16_x8<<<(nW8 + 255) / 256, 256, 0, stream>>>(Wt, Wbf, nW8);
        gemm_fusedcast<<<dim3(M_DIM / 128 * (N_DIM / 512)), 512, 0, stream>>>(
            X, Wbf, bias, decay, nullptr, out, nullptr);
        scan_f32_inplace<<<512, 64, 0, stream>>>(out, decay);
    } else {
        gemm_naive<<<dim3(N_DIM / 16, M_DIM / 16), dim3(16, 16), 0, stream>>>(X, Wt, bias, out);
        scan_f32_inplace<<<512, 64, 0, stream>>>(out, decay);
    }
}